// Round 9
// baseline (13582.019 us; speedup 1.0000x reference)
//
#include <hip/hip_runtime.h>

// ---------------- problem dims ----------------
constexpr int BB = 16;       // batch
constexpr int TT = 256;      // seq len
constexpr int IN0 = 512;     // input dim (layer 0)
constexpr int HH = 1024;     // hidden
constexpr int GG = 4096;     // 4*H gates
constexpr int NLAYERS = 8;
constexpr int NWG = 256;     // scan workgroups (1 per CU)

// ---------------- ws layout (bytes) ----------------
constexpr size_t XG_OFF   = 0;                         // xg2 [t*16+b][4096] fp32 : 64 MB
constexpr size_t REG0_OFF = 67108864;                  // 16 MB region 0 (Wcv / hs even layers)
constexpr size_t REG1_OFF = REG0_OFF + 16777216;       // 16 MB region 1 (Xcv0 / Wcv / hs odd)
constexpr size_t HG2_OFF  = REG1_OFF + 16777216;       // h parity packed: 2 x 16384 u32 = 128 KB
constexpr size_t FC1_OFF  = HG2_OFF + 131072;
constexpr size_t FC2_OFF  = FC1_OFF + 32768;
constexpr size_t BAR_OFF  = FC2_OFF + 16384;           // flags: 256 dwords (1 KB)
// flags[wg]: monotonic epoch, = wantbase + t + 1 once WG wg's h(t) is at coherence pt

// ---------------- scan LDS (bytes/floats) ----------------
constexpr int HLO_B = 34816;       // h-lo blocks base (hi at 0), both [128 kk][16 b] 16B, stride 272B
constexpr int PART_F = 17408;      // float idx: [4 waves][16 r pad17]
constexpr int GV_F = 18496;        // 256 floats
constexpr int SMEM_BYTES = 90112;  // pad >80K to force 1 WG/CU

typedef __attribute__((ext_vector_type(8))) short bf16x8;
typedef __attribute__((ext_vector_type(4))) float f32x4;

__device__ __forceinline__ unsigned short f2bf(float f)
{
    union { float f; unsigned u; } v{f};
    unsigned r = v.u + 0x7FFFu + ((v.u >> 16) & 1u);   // RNE
    return (unsigned short)(r >> 16);
}
__device__ __forceinline__ float bf2f(unsigned short h)
{
    union { unsigned u; float f; } v{(unsigned)h << 16};
    return v.f;
}

// ---------------- split conversion: fp32 -> bf16 hi + bf16 lo ----------------
__global__ __launch_bounds__(256) void conv_split(const float* __restrict__ in,
                                                  ushort* __restrict__ oh,
                                                  ushort* __restrict__ ol, int n4)
{
    int g = blockIdx.x * blockDim.x + threadIdx.x;
    if (g >= n4) return;
    float4 f = ((const float4*)in)[g];
    ushort4 h, l;
    h.x = f2bf(f.x); l.x = f2bf(f.x - bf2f(h.x));
    h.y = f2bf(f.y); l.y = f2bf(f.y - bf2f(h.y));
    h.z = f2bf(f.z); l.z = f2bf(f.z - bf2f(h.z));
    h.w = f2bf(f.w); l.w = f2bf(f.w - bf2f(h.w));
    ((ushort4*)oh)[g] = h;
    ((ushort4*)ol)[g] = l;
}

// ---------------- MFMA GEMM (unchanged from round 8, verified) ----------------
__global__ __launch_bounds__(256) void gemm_mfma(const ushort* __restrict__ Ah,
                                                 const ushort* __restrict__ Al,
                                                 const ushort* __restrict__ Wh,
                                                 const ushort* __restrict__ Wl,
                                                 const float* __restrict__ bih,
                                                 const float* __restrict__ bhh,
                                                 float* __restrict__ out, int K)
{
    __shared__ ushort lds[2][128 * 72];
    const int tid = threadIdx.x;
    const int w = tid >> 6, ln = tid & 63;
    const int m0 = blockIdx.y * 128, n0 = blockIdx.x * 128;
    const int arow = (w >> 1) * 64, bcol = (w & 1) * 64;
    const int lm = ln & 15, lk = (ln >> 4) * 8;
    const int sr = tid >> 3, sc = (tid & 7) * 8;

    f32x4 acc[4][4] = {};

#pragma unroll
    for (int s = 0; s < 3; ++s) {
        const ushort* Asrc = (s < 2) ? Ah : Al;
        const ushort* Bsrc = (s == 1) ? Wl : Wh;
        for (int k0 = 0; k0 < K; k0 += 64) {
            __syncthreads();
#pragma unroll
            for (int i = 0; i < 4; ++i) {
                int r = sr + 32 * i;
                *(uint4*)&lds[0][r * 72 + sc] =
                    *(const uint4*)(Asrc + (size_t)(m0 + r) * K + k0 + sc);
                *(uint4*)&lds[1][r * 72 + sc] =
                    *(const uint4*)(Bsrc + (size_t)(n0 + r) * K + k0 + sc);
            }
            __syncthreads();
#pragma unroll
            for (int ks = 0; ks < 2; ++ks) {
                bf16x8 af[4], bf[4];
#pragma unroll
                for (int i = 0; i < 4; ++i)
                    af[i] = *(const bf16x8*)&lds[0][(arow + i * 16 + lm) * 72 + ks * 32 + lk];
#pragma unroll
                for (int j = 0; j < 4; ++j)
                    bf[j] = *(const bf16x8*)&lds[1][(bcol + j * 16 + lm) * 72 + ks * 32 + lk];
#pragma unroll
                for (int i = 0; i < 4; ++i)
#pragma unroll
                    for (int j = 0; j < 4; ++j)
                        acc[i][j] = __builtin_amdgcn_mfma_f32_16x16x32_bf16(
                            af[i], bf[j], acc[i][j], 0, 0, 0);
            }
        }
    }

#pragma unroll
    for (int j = 0; j < 4; ++j) {
        const int n = n0 + bcol + j * 16 + lm;
        const float bsum = bih[n] + bhh[n];
#pragma unroll
        for (int i = 0; i < 4; ++i) {
            const int mrow = m0 + arow + i * 16 + (ln >> 4) * 4;
#pragma unroll
            for (int r = 0; r < 4; ++r) {
                const int m = mrow + r;
                const int bb = m >> 8, tt = m & 255;
                out[(size_t)(tt * 16 + bb) * GG + n] = acc[i][j][r] + bsum;
            }
        }
    }
}

__device__ __forceinline__ float sigf(float x) { return 1.0f / (1.0f + expf(-x)); }

// ---------------- per-layer LSTM scan: MFMA dot + flat per-producer flag sync --------
// WG wg owns h-cols j0=4wg..4wg+3 -> 16 gate rows grow(r)=(r>>2)*1024+j0+(r&3)
// h exchanged packed (bf16 hi | lo<<16) through parity buffers; flags are per-WG
// monotonic epochs; consumer wave0 reads all 256 flags in one wave-wide load.
__global__ __launch_bounds__(256, 1) void lstm_scan(const float* __restrict__ Whh,
                                                    const float* __restrict__ xg,
                                                    ushort* __restrict__ hseq_hi,
                                                    ushort* __restrict__ hseq_lo,
                                                    unsigned* __restrict__ hglob2p,
                                                    unsigned* __restrict__ flags,
                                                    unsigned wantbase)
{
    extern __shared__ float smem[];
    char* smb = (char*)smem;

    const int tid = threadIdx.x;
    const int wg  = blockIdx.x;
    const int j0  = wg << 2;
    const int w   = tid >> 6;
    const int ln  = tid & 63;
    const int m   = ln & 15;
    const int kq  = ln >> 4;

    // ---- preload W fragments (step-invariant): 8 ksteps x (hi,lo)
    bf16x8 wf_hi[8], wf_lo[8];
    {
        const int grow = ((m >> 2) << 10) + j0 + (m & 3);
        const float* wrow = Whh + (size_t)grow * 1024 + (w << 8) + (kq << 3);
#pragma unroll
        for (int s = 0; s < 8; ++s) {
            float4 f0 = *(const float4*)(wrow + s * 32);
            float4 f1 = *(const float4*)(wrow + s * 32 + 4);
            float fv[8] = {f0.x, f0.y, f0.z, f0.w, f1.x, f1.y, f1.z, f1.w};
            bf16x8 h8, l8;
#pragma unroll
            for (int i = 0; i < 8; ++i) {
                unsigned short hb = f2bf(fv[i]);
                float r = fv[i] - bf2f(hb);
                h8[i] = (short)hb;
                l8[i] = (short)f2bf(r);
            }
            wf_hi[s] = h8;
            wf_lo[s] = l8;
        }
    }

    const int bidx = ln >> 4;
    const int jj   = ln & 15;
    const int kkloc = jj >> 1;
    const int sub   = (jj & 1) * 8;

    const int r_red = tid >> 4, b_red = tid & 15;
    const int grow_red = ((r_red >> 2) << 10) + j0 + (r_red & 3);
    const int jl = tid >> 4, bg = tid & 15;      // gate lanes (tid<64)

    float c_state = 0.0f;
    float xg_pref = xg[(size_t)(0 * 16 + b_red) * GG + grow_red];

    for (int t = 0; t < TT; ++t) {
        f32x4 asum = {0.f, 0.f, 0.f, 0.f};

        if (t > 0) {
            // ---- wait: all 256 producer flags >= wantbase+t (h(t-1) published)
            // wave0: each lane checks 4 flags via one dwordx4; whole array in 1 wave-load
            if (tid < 64) {
                const unsigned tgt = wantbase + (unsigned)t;
                const unsigned* fp = flags + (tid << 2);
                while (true) {
                    uint4 f;
                    asm volatile("global_load_dwordx4 %0, %1, off sc0 sc1\n\t"
                                 "s_waitcnt vmcnt(0)"
                                 : "=&v"(f) : "v"(fp) : "memory");
                    int ok = (f.x >= tgt) && (f.y >= tgt) && (f.z >= tgt) && (f.w >= tgt);
                    if (__all(ok)) break;
                    __builtin_amdgcn_s_sleep(1);
                }
            }
            __syncthreads();

            // h(t-1) packed from parity buffer -> regs
            const uint4* hload = (const uint4*)(hglob2p + (((t - 1) & 1) << 14));
            uint4 v[4][4];
#pragma unroll
            for (int c = 0; c < 4; ++c) {
                const uint4* p = hload + ((w << 2) + c) * 256 + ln;
                asm volatile(
                    "global_load_dwordx4 %0, %4, off sc0 sc1\n\t"
                    "global_load_dwordx4 %1, %4, off offset:1024 sc0 sc1\n\t"
                    "global_load_dwordx4 %2, %4, off offset:2048 sc0 sc1\n\t"
                    "global_load_dwordx4 %3, %4, off offset:3072 sc0 sc1"
                    : "=&v"(v[c][0]), "=&v"(v[c][1]), "=&v"(v[c][2]), "=&v"(v[c][3])
                    : "v"(p) : "memory");
            }
            asm volatile("s_waitcnt vmcnt(0)" ::: "memory");
            __builtin_amdgcn_sched_barrier(0);

            // unpack hi/lo pairs -> LDS octet blocks [kk][b] (wave-private region)
#pragma unroll
            for (int c = 0; c < 4; ++c) {
                const int kk = ((w << 2) + c) * 8 + kkloc;
#pragma unroll
                for (int i = 0; i < 4; ++i) {
                    const int b = (i << 2) + bidx;
                    uint4 pv = v[c][i];
                    uint2 uh = {(pv.x & 0xFFFFu) | (pv.y << 16),
                                (pv.z & 0xFFFFu) | (pv.w << 16)};
                    uint2 ul = {(pv.x >> 16) | (pv.y & 0xFFFF0000u),
                                (pv.z >> 16) | (pv.w & 0xFFFF0000u)};
                    char* base = smb + kk * 272 + b * 16 + sub;
                    *(uint2*)(base) = uh;
                    *(uint2*)(base + HLO_B) = ul;
                }
            }
            asm volatile("s_waitcnt lgkmcnt(0)" ::: "memory");
            __builtin_amdgcn_sched_barrier(0);
            __builtin_amdgcn_wave_barrier();

            f32x4 aA = {0.f, 0.f, 0.f, 0.f};
            f32x4 aB = {0.f, 0.f, 0.f, 0.f};
            f32x4 aC = {0.f, 0.f, 0.f, 0.f};
            const char* hb0 = smb + ((w << 5) + kq) * 272 + m * 16;
#pragma unroll
            for (int s = 0; s < 8; ++s) {
                bf16x8 bh = *(const bf16x8*)(hb0 + s * 1088);
                bf16x8 bl = *(const bf16x8*)(hb0 + HLO_B + s * 1088);
                aA = __builtin_amdgcn_mfma_f32_16x16x32_bf16(wf_hi[s], bh, aA, 0, 0, 0);
                aB = __builtin_amdgcn_mfma_f32_16x16x32_bf16(wf_hi[s], bl, aB, 0, 0, 0);
                aC = __builtin_amdgcn_mfma_f32_16x16x32_bf16(wf_lo[s], bh, aC, 0, 0, 0);
            }
            asum = aA + aB;
            asum = asum + aC;
        }

#pragma unroll
        for (int r = 0; r < 4; ++r)
            smem[PART_F + w * 272 + ((kq << 2) + r) * 17 + m] = asum[r];
        __syncthreads();

        smem[GV_F + tid] = smem[PART_F + (tid >> 4) * 17 + (tid & 15)]
                         + smem[PART_F + 272 + (tid >> 4) * 17 + (tid & 15)]
                         + smem[PART_F + 544 + (tid >> 4) * 17 + (tid & 15)]
                         + smem[PART_F + 816 + (tid >> 4) * 17 + (tid & 15)]
                         + xg_pref;
        __syncthreads();

        float xg_next = 0.f;
        if (t + 1 < TT)
            xg_next = xg[(size_t)((t + 1) * 16 + b_red) * GG + grow_red];

        if (tid < 64) {
            const int col = j0 + jl;
            float iv = smem[GV_F + (jl     ) * 16 + bg];
            float fv = smem[GV_F + (jl +  4) * 16 + bg];
            float gg = smem[GV_F + (jl +  8) * 16 + bg];
            float ov = smem[GV_F + (jl + 12) * 16 + bg];
            c_state = sigf(fv) * c_state + sigf(iv) * tanhf(gg);
            float hval = sigf(ov) * tanhf(c_state);
            // split once; packed device-coherent store into parity buffer t&1
            unsigned short hh_ = f2bf(hval);
            unsigned short hl_ = f2bf(hval - bf2f(hh_));
            unsigned pk = (unsigned)hh_ | ((unsigned)hl_ << 16);
            unsigned* hdst = hglob2p + ((t & 1) << 14) +
                             ((col >> 6) << 10) + (bg << 6) + (col & 63);
            asm volatile("global_store_dword %0, %1, off sc0 sc1"
                         :: "v"(hdst), "v"(pk) : "memory");
            size_t idx = (size_t)(bg * TT + t) * HH + col;
            hseq_hi[idx] = hh_;                      // next-layer GEMM input (plain)
            hseq_lo[idx] = hl_;
        }
        if (tid == 0) {
            // release: wave0's packed-h stores acked at coherence point, then publish
            asm volatile("s_waitcnt vmcnt(0)" ::: "memory");
            __hip_atomic_store(flags + wg, wantbase + (unsigned)t + 1u,
                               __ATOMIC_RELAXED, __HIP_MEMORY_SCOPE_AGENT);
        }
        xg_pref = xg_next;
    }
}

// ---------------- FC head ----------------
__global__ void fc_relu_split(const ushort* __restrict__ ih, const ushort* __restrict__ il,
                              const float* __restrict__ w, const float* __restrict__ b,
                              float* __restrict__ out, int N, int K)
{
    int g = blockIdx.x * blockDim.x + threadIdx.x;
    if (g >= BB * N) return;
    int bi = g / N, n = g - bi * N;
    const ushort* ph = ih + (size_t)(bi * 256 + 255) * 1024;
    const ushort* pl = il + (size_t)(bi * 256 + 255) * 1024;
    const float* wp = w + (size_t)n * K;
    float s = 0.f;
    for (int k = 0; k < K; k += 4) {
        ushort4 uh = *(const ushort4*)(ph + k);
        ushort4 ul = *(const ushort4*)(pl + k);
        float4 q = *(const float4*)(wp + k);
        s += (bf2f(uh.x) + bf2f(ul.x)) * q.x + (bf2f(uh.y) + bf2f(ul.y)) * q.y +
             (bf2f(uh.z) + bf2f(ul.z)) * q.z + (bf2f(uh.w) + bf2f(ul.w)) * q.w;
    }
    s += b[n];
    out[g] = fmaxf(s, 0.f);
}

__global__ void fc_relu(const float* __restrict__ in, const float* __restrict__ w,
                        const float* __restrict__ b, float* __restrict__ out,
                        int N, int K, int do_relu)
{
    int g = blockIdx.x * blockDim.x + threadIdx.x;
    if (g >= BB * N) return;
    int bi = g / N, n = g - bi * N;
    const float* ip = in + (size_t)bi * K;
    const float* wp = w + (size_t)n * K;
    float s = 0.f;
    for (int k = 0; k < K; k += 4) {
        float4 a = *(const float4*)(ip + k);
        float4 q = *(const float4*)(wp + k);
        s += a.x * q.x + a.y * q.y + a.z * q.z + a.w * q.w;
    }
    s += b[n];
    if (do_relu) s = fmaxf(s, 0.f);
    out[g] = s;
}

// ---------------- launch ----------------
extern "C" void kernel_launch(void* const* d_in, const int* in_sizes, int n_in,
                              void* d_out, int out_size, void* d_ws, size_t ws_size,
                              hipStream_t stream)
{
    const float* x    = (const float*)d_in[0];
    const float* Wih0 = (const float*)d_in[1];
    const float* WihR = (const float*)d_in[2];
    const float* Whh  = (const float*)d_in[3];
    const float* bih  = (const float*)d_in[4];
    const float* bhh  = (const float*)d_in[5];
    const float* fc1w = (const float*)d_in[6];
    const float* fc1b = (const float*)d_in[7];
    const float* fc2w = (const float*)d_in[8];
    const float* fc2b = (const float*)d_in[9];
    const float* fc3w = (const float*)d_in[10];
    const float* fc3b = (const float*)d_in[11];
    float* out = (float*)d_out;
    char* ws = (char*)d_ws;

    float* xg       = (float*)(ws + XG_OFF);
    ushort* reg_[2] = {(ushort*)(ws + REG0_OFF), (ushort*)(ws + REG1_OFF)};
    unsigned* hglob2p = (unsigned*)(ws + HG2_OFF);
    float* fc1o     = (float*)(ws + FC1_OFF);
    float* fc2o     = (float*)(ws + FC2_OFF);
    unsigned* flags = (unsigned*)(ws + BAR_OFF);

    (void)hipFuncSetAttribute((const void*)lstm_scan,
                              hipFuncAttributeMaxDynamicSharedMemorySize, SMEM_BYTES);
    (void)hipMemsetAsync(ws + BAR_OFF, 0, 4096, stream);   // flags = 0 (monotonic)

    // layer-0 X conversion into region 1 (dead before Wcv(1) is written)
    ushort* xcv_hi = reg_[1];
    ushort* xcv_lo = reg_[1] + 2097152;
    conv_split<<<2048, 256, 0, stream>>>(x, xcv_hi, xcv_lo, (BB * TT * IN0) / 4);

    for (int l = 0; l < NLAYERS; ++l) {
        const int K = (l == 0) ? IN0 : HH;
        const float* Wl_f = (l == 0) ? Wih0 : (WihR + (size_t)(l - 1) * GG * HH);

        ushort* wh = reg_[l & 1];
        ushort* wl = wh + 4194304;
        const int n4 = GG * K / 4;
        conv_split<<<(n4 + 255) / 256, 256, 0, stream>>>(Wl_f, wh, wl, n4);

        const ushort* ah = (l == 0) ? xcv_hi : reg_[(l - 1) & 1];
        const ushort* al = (l == 0) ? xcv_lo : (reg_[(l - 1) & 1] + 4194304);

        gemm_mfma<<<dim3(32, 32), 256, 0, stream>>>(
            ah, al, wh, wl, bih + (size_t)l * GG, bhh + (size_t)l * GG, xg, K);

        ushort* hs_hi = reg_[l & 1];
        ushort* hs_lo = reg_[l & 1] + 4194304;
        const float* whh_l = Whh + (size_t)l * GG * HH;
        unsigned wantbase = (unsigned)(TT * l);
        void* args[7] = {(void*)&whh_l, (void*)&xg, (void*)&hs_hi, (void*)&hs_lo,
                         (void*)&hglob2p, (void*)&flags, (void*)&wantbase};
        hipError_t e = hipLaunchCooperativeKernel((void*)lstm_scan, dim3(NWG), dim3(256),
                                                  args, SMEM_BYTES, stream);
        if (e != hipSuccess) {
            lstm_scan<<<dim3(NWG), dim3(256), SMEM_BYTES, stream>>>(
                whh_l, xg, hs_hi, hs_lo, hglob2p, flags, wantbase);
        }
    }

    // FC head: hs(7) is in region 1
    fc_relu_split<<<32, 256, 0, stream>>>(reg_[1], reg_[1] + 4194304,
                                          fc1w, fc1b, fc1o, 512, 1024);
    fc_relu<<<16, 256, 0, stream>>>(fc1o, fc2w, fc2b, fc2o, 256, 512, 1);
    fc_relu<<<1, 16, 0, stream>>>(fc2o, fc3w, fc3b, out, 1, 256, 0);
}

// Round 10
// 10517.635 us; speedup vs baseline: 1.2914x; 1.2914x over previous
//
#include <hip/hip_runtime.h>

// ---------------- problem dims ----------------
constexpr int BB = 16;       // batch
constexpr int TT = 256;      // seq len
constexpr int IN0 = 512;     // input dim (layer 0)
constexpr int HH = 1024;     // hidden
constexpr int GG = 4096;     // 4*H gates
constexpr int NLAYERS = 8;
constexpr int NWG = 128;     // scan workgroups (512 thr each)

// ---------------- ws layout (bytes) ----------------
constexpr size_t XG_OFF   = 0;                         // xg2 [t*16+b][4096] fp32 : 64 MB
constexpr size_t REG0_OFF = 67108864;                  // 16 MB region 0 (Wcv / hs even layers)
constexpr size_t REG1_OFF = REG0_OFF + 16777216;       // 16 MB region 1 (Xcv0 / Wcv / hs odd)
constexpr size_t HG2_OFF  = REG1_OFF + 16777216;       // h parity packed: 2 x 16384 u32 = 128 KB
constexpr size_t FC1_OFF  = HG2_OFF + 131072;
constexpr size_t FC2_OFF  = FC1_OFF + 32768;
constexpr size_t BAR_OFF  = FC2_OFF + 16384;           // barrier state (4 KB)
// bar (unsigned): arrive[g] @ g*16 (g<8); root @ 256; gen copy[g] @ 512+g*16

// ---------------- scan LDS (bytes/floats) ----------------
constexpr int HLO_B = 34816;       // h-lo blocks base (hi at 0): [128 kk][16 b] 16B, stride 272B
constexpr int PART_F = 17408;      // float idx (@69632B): [8 waves][16 r pad17]
constexpr int XGB_F  = 19584;      // 512 floats: xg staged [32 r][16 b]
constexpr int SMEM_BYTES = 90112;  // pad: 1 WG/CU

typedef __attribute__((ext_vector_type(8))) short bf16x8;
typedef __attribute__((ext_vector_type(4))) float f32x4;

__device__ __forceinline__ unsigned short f2bf(float f)
{
    union { float f; unsigned u; } v{f};
    unsigned r = v.u + 0x7FFFu + ((v.u >> 16) & 1u);   // RNE
    return (unsigned short)(r >> 16);
}
__device__ __forceinline__ float bf2f(unsigned short h)
{
    union { unsigned u; float f; } v{(unsigned)h << 16};
    return v.f;
}

// ---------------- split conversion: fp32 -> bf16 hi + bf16 lo ----------------
__global__ __launch_bounds__(256) void conv_split(const float* __restrict__ in,
                                                  ushort* __restrict__ oh,
                                                  ushort* __restrict__ ol, int n4)
{
    int g = blockIdx.x * blockDim.x + threadIdx.x;
    if (g >= n4) return;
    float4 f = ((const float4*)in)[g];
    ushort4 h, l;
    h.x = f2bf(f.x); l.x = f2bf(f.x - bf2f(h.x));
    h.y = f2bf(f.y); l.y = f2bf(f.y - bf2f(h.y));
    h.z = f2bf(f.z); l.z = f2bf(f.z - bf2f(h.z));
    h.w = f2bf(f.w); l.w = f2bf(f.w - bf2f(h.w));
    ((ushort4*)oh)[g] = h;
    ((ushort4*)ol)[g] = l;
}

// ---------------- MFMA GEMM (unchanged, verified) ----------------
__global__ __launch_bounds__(256) void gemm_mfma(const ushort* __restrict__ Ah,
                                                 const ushort* __restrict__ Al,
                                                 const ushort* __restrict__ Wh,
                                                 const ushort* __restrict__ Wl,
                                                 const float* __restrict__ bih,
                                                 const float* __restrict__ bhh,
                                                 float* __restrict__ out, int K)
{
    __shared__ ushort lds[2][128 * 72];
    const int tid = threadIdx.x;
    const int w = tid >> 6, ln = tid & 63;
    const int m0 = blockIdx.y * 128, n0 = blockIdx.x * 128;
    const int arow = (w >> 1) * 64, bcol = (w & 1) * 64;
    const int lm = ln & 15, lk = (ln >> 4) * 8;
    const int sr = tid >> 3, sc = (tid & 7) * 8;

    f32x4 acc[4][4] = {};

#pragma unroll
    for (int s = 0; s < 3; ++s) {
        const ushort* Asrc = (s < 2) ? Ah : Al;
        const ushort* Bsrc = (s == 1) ? Wl : Wh;
        for (int k0 = 0; k0 < K; k0 += 64) {
            __syncthreads();
#pragma unroll
            for (int i = 0; i < 4; ++i) {
                int r = sr + 32 * i;
                *(uint4*)&lds[0][r * 72 + sc] =
                    *(const uint4*)(Asrc + (size_t)(m0 + r) * K + k0 + sc);
                *(uint4*)&lds[1][r * 72 + sc] =
                    *(const uint4*)(Bsrc + (size_t)(n0 + r) * K + k0 + sc);
            }
            __syncthreads();
#pragma unroll
            for (int ks = 0; ks < 2; ++ks) {
                bf16x8 af[4], bf[4];
#pragma unroll
                for (int i = 0; i < 4; ++i)
                    af[i] = *(const bf16x8*)&lds[0][(arow + i * 16 + lm) * 72 + ks * 32 + lk];
#pragma unroll
                for (int j = 0; j < 4; ++j)
                    bf[j] = *(const bf16x8*)&lds[1][(bcol + j * 16 + lm) * 72 + ks * 32 + lk];
#pragma unroll
                for (int i = 0; i < 4; ++i)
#pragma unroll
                    for (int j = 0; j < 4; ++j)
                        acc[i][j] = __builtin_amdgcn_mfma_f32_16x16x32_bf16(
                            af[i], bf[j], acc[i][j], 0, 0, 0);
            }
        }
    }

#pragma unroll
    for (int j = 0; j < 4; ++j) {
        const int n = n0 + bcol + j * 16 + lm;
        const float bsum = bih[n] + bhh[n];
#pragma unroll
        for (int i = 0; i < 4; ++i) {
            const int mrow = m0 + arow + i * 16 + (ln >> 4) * 4;
#pragma unroll
            for (int r = 0; r < 4; ++r) {
                const int m = mrow + r;
                const int bb = m >> 8, tt = m & 255;
                out[(size_t)(tt * 16 + bb) * GG + n] = acc[i][j][r] + bsum;
            }
        }
    }
}

__device__ __forceinline__ float sigf(float x) { return 1.0f / (1.0f + expf(-x)); }

// ---------------- per-layer LSTM scan: 128 WG x 512 thr, MFMA dot, tree barrier ------
// WG wg owns h-cols j0=8wg..8wg+7 -> 32 gate rows r: gate=r>>3, col=j0+(r&7).
// Wave w: tile t_w=w&1 (rows t_w*16..+15), kslice s_w=w>>1 (k [256*s_w,+256)).
// Wave w stages h chunks {2w,2w+1} (k [128w,+128)) into LDS (cross-wave reads -> sync).
__global__ __launch_bounds__(512, 1) void lstm_scan(const float* __restrict__ Whh,
                                                    const float* __restrict__ xg,
                                                    ushort* __restrict__ hseq_hi,
                                                    ushort* __restrict__ hseq_lo,
                                                    unsigned* __restrict__ hglob2p,
                                                    unsigned* __restrict__ bar,
                                                    unsigned wantbase)
{
    extern __shared__ float smem[];
    char* smb = (char*)smem;

    const int tid = threadIdx.x;
    const int wg  = blockIdx.x;
    const int j0  = wg << 3;
    const int w   = tid >> 6;
    const int ln  = tid & 63;
    const int m   = ln & 15;     // tile-row (A) / batch-col (B) lane index
    const int kq  = ln >> 4;     // k-quarter in K=32 MFMA tile
    const int t_w = w & 1;       // output tile (0: gates i,f ; 1: gates g,o)
    const int s_w = w >> 1;      // k-slice

    // ---- preload W fragments (step-invariant): 8 ksteps x (hi,lo)
    bf16x8 wf_hi[8], wf_lo[8];
    {
        const int r = t_w * 16 + m;                        // gate row in [0,32)
        const int grow = ((r >> 3) << 10) + j0 + (r & 7);
        const float* wrow = Whh + (size_t)grow * 1024 + (s_w << 8) + (kq << 3);
#pragma unroll
        for (int s = 0; s < 8; ++s) {
            float4 f0 = *(const float4*)(wrow + s * 32);
            float4 f1 = *(const float4*)(wrow + s * 32 + 4);
            float fv[8] = {f0.x, f0.y, f0.z, f0.w, f1.x, f1.y, f1.z, f1.w};
            bf16x8 h8, l8;
#pragma unroll
            for (int i = 0; i < 8; ++i) {
                unsigned short hb = f2bf(fv[i]);
                float rr = fv[i] - bf2f(hb);
                h8[i] = (short)hb;
                l8[i] = (short)f2bf(rr);
            }
            wf_hi[s] = h8;
            wf_lo[s] = l8;
        }
    }

    // staging lane mapping
    const int bidx = ln >> 4;
    const int jj   = ln & 15;
    const int kkloc = jj >> 1;
    const int sub   = (jj & 1) * 8;

    // xg mapping: thread tid <-> (r_x = tid>>4 in [0,32), b_x = tid&15)
    const int r_x = tid >> 4, b_x = tid & 15;
    const int grow_x = ((r_x >> 3) << 10) + j0 + (r_x & 7);

    // gate lanes (tid<64): q = col-pair, b = batch
    const int q = tid >> 4, bg = tid & 15;

    // barrier pointers (tid0): 8 groups of 16 WGs
    unsigned* arr  = bar + ((wg >> 4) << 4);
    unsigned* root = bar + 256;
    unsigned* genc = bar + 512 + ((wg >> 4) << 4);

    float cs0 = 0.0f, cs1 = 0.0f;    // c-state for cols j0+2q, j0+2q+1

    float xg_pref = xg[(size_t)(0 * 16 + b_x) * GG + grow_x];

    for (int t = 0; t < TT; ++t) {
        if (t > 0) {
            if (tid == 0) {
                const unsigned tgt = wantbase + (unsigned)t;
                while (__hip_atomic_load(genc, __ATOMIC_RELAXED, __HIP_MEMORY_SCOPE_AGENT) < tgt)
                    __builtin_amdgcn_s_sleep(1);
            }
        }
        __syncthreads();                       // release waves; also fences prev gate reads

        smem[XGB_F + tid] = xg_pref;           // stage xg(t) (visible after next sync)

        if (t > 0) {
            // h(t-1) packed from parity buffer -> regs (wave w: chunks 2w, 2w+1)
            const uint4* hload = (const uint4*)(hglob2p + (((t - 1) & 1) << 14));
            uint4 v[2][4];
#pragma unroll
            for (int cc = 0; cc < 2; ++cc) {
                const uint4* p = hload + ((w << 1) + cc) * 256 + ln;
                asm volatile(
                    "global_load_dwordx4 %0, %4, off sc0 sc1\n\t"
                    "global_load_dwordx4 %1, %4, off offset:1024 sc0 sc1\n\t"
                    "global_load_dwordx4 %2, %4, off offset:2048 sc0 sc1\n\t"
                    "global_load_dwordx4 %3, %4, off offset:3072 sc0 sc1"
                    : "=&v"(v[cc][0]), "=&v"(v[cc][1]), "=&v"(v[cc][2]), "=&v"(v[cc][3])
                    : "v"(p) : "memory");
            }
            asm volatile("s_waitcnt vmcnt(0)" ::: "memory");
            __builtin_amdgcn_sched_barrier(0);

            // unpack hi/lo -> LDS octet blocks [kk][b]
#pragma unroll
            for (int cc = 0; cc < 2; ++cc) {
                const int kk = ((w << 1) + cc) * 8 + kkloc;
#pragma unroll
                for (int i = 0; i < 4; ++i) {
                    const int b = (i << 2) + bidx;
                    uint4 pv = v[cc][i];
                    uint2 uh = {(pv.x & 0xFFFFu) | (pv.y << 16),
                                (pv.z & 0xFFFFu) | (pv.w << 16)};
                    uint2 ul = {(pv.x >> 16) | (pv.y & 0xFFFF0000u),
                                (pv.z >> 16) | (pv.w & 0xFFFF0000u)};
                    char* base = smb + kk * 272 + b * 16 + sub;
                    *(uint2*)(base) = uh;
                    *(uint2*)(base + HLO_B) = ul;
                }
            }
        }
        __syncthreads();                       // stage + xg visible to all waves

        f32x4 asum = {0.f, 0.f, 0.f, 0.f};
        if (t > 0) {
            f32x4 aA = {0.f, 0.f, 0.f, 0.f};
            f32x4 aB = {0.f, 0.f, 0.f, 0.f};
            f32x4 aC = {0.f, 0.f, 0.f, 0.f};
            const char* hb0 = smb + ((s_w << 5) + kq) * 272 + m * 16;
#pragma unroll
            for (int s = 0; s < 8; ++s) {
                bf16x8 bh = *(const bf16x8*)(hb0 + s * 1088);
                bf16x8 bl = *(const bf16x8*)(hb0 + HLO_B + s * 1088);
                aA = __builtin_amdgcn_mfma_f32_16x16x32_bf16(wf_hi[s], bh, aA, 0, 0, 0);
                aB = __builtin_amdgcn_mfma_f32_16x16x32_bf16(wf_hi[s], bl, aB, 0, 0, 0);
                aC = __builtin_amdgcn_mfma_f32_16x16x32_bf16(wf_lo[s], bh, aC, 0, 0, 0);
            }
            asum = aA + aB;
            asum = asum + aC;
        }

        // partials: D row = kq*4+reg (tile row), col = m (batch)
#pragma unroll
        for (int r = 0; r < 4; ++r)
            smem[PART_F + w * 272 + ((kq << 2) + r) * 17 + m] = asum[r];
        __syncthreads();

        // prefetch next xg (hides under gates + barrier)
        float xg_next = 0.f;
        if (t + 1 < TT)
            xg_next = xg[(size_t)((t + 1) * 16 + b_x) * GG + grow_x];

        if (tid < 64) {
            // fused reduce + gates for cols c0=2q, c1=2q+1
#pragma unroll
            for (int cc = 0; cc < 2; ++cc) {
                const int ch = 2 * q + cc;
                float iv = smem[XGB_F + (ch     ) * 16 + bg];
                float fv = smem[XGB_F + (ch +  8) * 16 + bg];
                float gv = smem[XGB_F + (ch + 16) * 16 + bg];
                float ov = smem[XGB_F + (ch + 24) * 16 + bg];
#pragma unroll
                for (int s = 0; s < 4; ++s) {
                    iv += smem[PART_F + (2 * s    ) * 272 + (ch    ) * 17 + bg];
                    fv += smem[PART_F + (2 * s    ) * 272 + (ch + 8) * 17 + bg];
                    gv += smem[PART_F + (2 * s + 1) * 272 + (ch    ) * 17 + bg];
                    ov += smem[PART_F + (2 * s + 1) * 272 + (ch + 8) * 17 + bg];
                }
                float& cs = cc ? cs1 : cs0;
                cs = sigf(fv) * cs + sigf(iv) * tanhf(gv);
                float hval = sigf(ov) * tanhf(cs);
                unsigned short hh_ = f2bf(hval);
                unsigned short hl_ = f2bf(hval - bf2f(hh_));
                unsigned pk = (unsigned)hh_ | ((unsigned)hl_ << 16);
                const int col = j0 + ch;
                unsigned* hdst = hglob2p + ((t & 1) << 14) +
                                 ((col >> 6) << 10) + (bg << 6) + (col & 63);
                asm volatile("global_store_dword %0, %1, off sc0 sc1"
                             :: "v"(hdst), "v"(pk) : "memory");
                // stash for hseq (stored after arrive, off sync path)
                if (cc == 0) { cs0 = cs; }
                smem[XGB_F + 512 + tid * 2 + cc] = __int_as_float((int)pk);
            }
        }

        if (t < TT - 1) {
            const unsigned target = wantbase + (unsigned)t + 1u;
            if (tid == 0) {
                asm volatile("s_waitcnt vmcnt(0)" ::: "memory");   // h stores acked
                unsigned a = __hip_atomic_fetch_add(arr, 1u, __ATOMIC_RELAXED, __HIP_MEMORY_SCOPE_AGENT);
                if (a == 15u) {
                    unsigned ra = __hip_atomic_fetch_add(root, 1u, __ATOMIC_RELAXED, __HIP_MEMORY_SCOPE_AGENT);
                    if (ra == 7u) {
                        __hip_atomic_store(root, 0u, __ATOMIC_RELAXED, __HIP_MEMORY_SCOPE_AGENT);
#pragma unroll
                        for (int i = 0; i < 8; ++i)
                            __hip_atomic_store(bar + (i << 4), 0u, __ATOMIC_RELAXED, __HIP_MEMORY_SCOPE_AGENT);
                        asm volatile("s_waitcnt vmcnt(0)" ::: "memory");
#pragma unroll
                        for (int i = 0; i < 8; ++i)
                            __hip_atomic_store(bar + 512 + (i << 4), target,
                                               __ATOMIC_RELAXED, __HIP_MEMORY_SCOPE_AGENT);
                    }
                }
            }
        }
        if (tid < 64) {   // hseq stores after arrive (plain, kernel-end visibility)
#pragma unroll
            for (int cc = 0; cc < 2; ++cc) {
                unsigned pk = (unsigned)__float_as_int(smem[XGB_F + 512 + tid * 2 + cc]);
                const int col = j0 + 2 * q + cc;
                size_t idx = (size_t)(bg * TT + t) * HH + col;
                hseq_hi[idx] = (ushort)(pk & 0xFFFFu);
                hseq_lo[idx] = (ushort)(pk >> 16);
            }
        }
        xg_pref = xg_next;
    }
}

// ---------------- FC head ----------------
__global__ void fc_relu_split(const ushort* __restrict__ ih, const ushort* __restrict__ il,
                              const float* __restrict__ w, const float* __restrict__ b,
                              float* __restrict__ out, int N, int K)
{
    int g = blockIdx.x * blockDim.x + threadIdx.x;
    if (g >= BB * N) return;
    int bi = g / N, n = g - bi * N;
    const ushort* ph = ih + (size_t)(bi * 256 + 255) * 1024;
    const ushort* pl = il + (size_t)(bi * 256 + 255) * 1024;
    const float* wp = w + (size_t)n * K;
    float s = 0.f;
    for (int k = 0; k < K; k += 4) {
        ushort4 uh = *(const ushort4*)(ph + k);
        ushort4 ul = *(const ushort4*)(pl + k);
        float4 qv = *(const float4*)(wp + k);
        s += (bf2f(uh.x) + bf2f(ul.x)) * qv.x + (bf2f(uh.y) + bf2f(ul.y)) * qv.y +
             (bf2f(uh.z) + bf2f(ul.z)) * qv.z + (bf2f(uh.w) + bf2f(ul.w)) * qv.w;
    }
    s += b[n];
    out[g] = fmaxf(s, 0.f);
}

__global__ void fc_relu(const float* __restrict__ in, const float* __restrict__ w,
                        const float* __restrict__ b, float* __restrict__ out,
                        int N, int K, int do_relu)
{
    int g = blockIdx.x * blockDim.x + threadIdx.x;
    if (g >= BB * N) return;
    int bi = g / N, n = g - bi * N;
    const float* ip = in + (size_t)bi * K;
    const float* wp = w + (size_t)n * K;
    float s = 0.f;
    for (int k = 0; k < K; k += 4) {
        float4 a = *(const float4*)(ip + k);
        float4 qv = *(const float4*)(wp + k);
        s += a.x * qv.x + a.y * qv.y + a.z * qv.z + a.w * qv.w;
    }
    s += b[n];
    if (do_relu) s = fmaxf(s, 0.f);
    out[g] = s;
}

// ---------------- launch ----------------
extern "C" void kernel_launch(void* const* d_in, const int* in_sizes, int n_in,
                              void* d_out, int out_size, void* d_ws, size_t ws_size,
                              hipStream_t stream)
{
    const float* x    = (const float*)d_in[0];
    const float* Wih0 = (const float*)d_in[1];
    const float* WihR = (const float*)d_in[2];
    const float* Whh  = (const float*)d_in[3];
    const float* bih  = (const float*)d_in[4];
    const float* bhh  = (const float*)d_in[5];
    const float* fc1w = (const float*)d_in[6];
    const float* fc1b = (const float*)d_in[7];
    const float* fc2w = (const float*)d_in[8];
    const float* fc2b = (const float*)d_in[9];
    const float* fc3w = (const float*)d_in[10];
    const float* fc3b = (const float*)d_in[11];
    float* out = (float*)d_out;
    char* ws = (char*)d_ws;

    float* xg       = (float*)(ws + XG_OFF);
    ushort* reg_[2] = {(ushort*)(ws + REG0_OFF), (ushort*)(ws + REG1_OFF)};
    unsigned* hglob2p = (unsigned*)(ws + HG2_OFF);
    float* fc1o     = (float*)(ws + FC1_OFF);
    float* fc2o     = (float*)(ws + FC2_OFF);
    unsigned* bar   = (unsigned*)(ws + BAR_OFF);

    (void)hipFuncSetAttribute((const void*)lstm_scan,
                              hipFuncAttributeMaxDynamicSharedMemorySize, SMEM_BYTES);
    (void)hipMemsetAsync(ws + BAR_OFF, 0, 4096, stream);   // arrive/root/gen = 0 (monotonic)

    // layer-0 X conversion into region 1 (dead before Wcv(1) is written)
    ushort* xcv_hi = reg_[1];
    ushort* xcv_lo = reg_[1] + 2097152;
    conv_split<<<2048, 256, 0, stream>>>(x, xcv_hi, xcv_lo, (BB * TT * IN0) / 4);

    for (int l = 0; l < NLAYERS; ++l) {
        const int K = (l == 0) ? IN0 : HH;
        const float* Wl_f = (l == 0) ? Wih0 : (WihR + (size_t)(l - 1) * GG * HH);

        ushort* wh = reg_[l & 1];
        ushort* wl = wh + 4194304;
        const int n4 = GG * K / 4;
        conv_split<<<(n4 + 255) / 256, 256, 0, stream>>>(Wl_f, wh, wl, n4);

        const ushort* ah = (l == 0) ? xcv_hi : reg_[(l - 1) & 1];
        const ushort* al = (l == 0) ? xcv_lo : (reg_[(l - 1) & 1] + 4194304);

        gemm_mfma<<<dim3(32, 32), 256, 0, stream>>>(
            ah, al, wh, wl, bih + (size_t)l * GG, bhh + (size_t)l * GG, xg, K);

        ushort* hs_hi = reg_[l & 1];
        ushort* hs_lo = reg_[l & 1] + 4194304;
        const float* whh_l = Whh + (size_t)l * GG * HH;
        unsigned wantbase = (unsigned)(TT * l);
        void* args[7] = {(void*)&whh_l, (void*)&xg, (void*)&hs_hi, (void*)&hs_lo,
                         (void*)&hglob2p, (void*)&bar, (void*)&wantbase};
        hipError_t e = hipLaunchCooperativeKernel((void*)lstm_scan, dim3(NWG), dim3(512),
                                                  args, SMEM_BYTES, stream);
        if (e != hipSuccess) {
            lstm_scan<<<dim3(NWG), dim3(512), SMEM_BYTES, stream>>>(
                whh_l, xg, hs_hi, hs_lo, hglob2p, bar, wantbase);
        }
    }

    // FC head: hs(7) is in region 1
    fc_relu_split<<<32, 256, 0, stream>>>(reg_[1], reg_[1] + 4194304,
                                          fc1w, fc1b, fc1o, 512, 1024);
    fc_relu<<<16, 256, 0, stream>>>(fc1o, fc2w, fc2b, fc2o, 256, 512, 1);
    fc_relu<<<1, 16, 0, stream>>>(fc2o, fc3w, fc3b, out, 1, 256, 0);
}

// Round 11
// 10507.074 us; speedup vs baseline: 1.2927x; 1.0010x over previous
//
#include <hip/hip_runtime.h>

// ---------------- problem dims ----------------
constexpr int BB = 16;       // batch
constexpr int TT = 256;      // seq len
constexpr int IN0 = 512;     // input dim (layer 0)
constexpr int HH = 1024;     // hidden
constexpr int GG = 4096;     // 4*H gates
constexpr int NLAYERS = 8;
constexpr int NWG = 128;     // scan workgroups (512 thr each)

// ---------------- ws layout (bytes) ----------------
constexpr size_t XG_OFF   = 0;                         // xg2 [t*16+b][4096] fp32 : 64 MB
constexpr size_t REG0_OFF = 67108864;                  // 16 MB region 0 (Wcv / hs even layers)
constexpr size_t REG1_OFF = REG0_OFF + 16777216;       // 16 MB region 1 (Xcv0 / Wcv / hs odd)
constexpr size_t HG2_OFF  = REG1_OFF + 16777216;       // h parity packed: 2 x 16384 u32 = 128 KB
constexpr size_t FC1_OFF  = HG2_OFF + 131072;
constexpr size_t FC2_OFF  = FC1_OFF + 32768;
constexpr size_t BAR_OFF  = FC2_OFF + 16384;           // barrier state (4 KB)
// bar (unsigned): arrive[g] @ g*16 (g<8); root @ 256; gen copy[g] @ 512+g*16

// ---------------- scan LDS (bytes/floats) ----------------
constexpr int HLO_B = 34816;       // h-lo blocks base (hi at 0): [128 kk][16 b] 16B, stride 272B
constexpr int PART_F = 17408;      // float idx (@69632B): [8 waves][16 r pad17]
constexpr int XGB_F  = 19584;      // 512 floats: xg staged [32 r][16 b]
constexpr int SMEM_BYTES = 90112;  // pad: 1 WG/CU

typedef __attribute__((ext_vector_type(8))) short bf16x8;
typedef __attribute__((ext_vector_type(4))) float f32x4;

__device__ __forceinline__ unsigned short f2bf(float f)
{
    union { float f; unsigned u; } v{f};
    unsigned r = v.u + 0x7FFFu + ((v.u >> 16) & 1u);   // RNE
    return (unsigned short)(r >> 16);
}
__device__ __forceinline__ float bf2f(unsigned short h)
{
    union { unsigned u; float f; } v{(unsigned)h << 16};
    return v.f;
}

// ---------------- split conversion: fp32 -> bf16 hi + bf16 lo ----------------
__global__ __launch_bounds__(256) void conv_split(const float* __restrict__ in,
                                                  ushort* __restrict__ oh,
                                                  ushort* __restrict__ ol, int n4)
{
    int g = blockIdx.x * blockDim.x + threadIdx.x;
    if (g >= n4) return;
    float4 f = ((const float4*)in)[g];
    ushort4 h, l;
    h.x = f2bf(f.x); l.x = f2bf(f.x - bf2f(h.x));
    h.y = f2bf(f.y); l.y = f2bf(f.y - bf2f(h.y));
    h.z = f2bf(f.z); l.z = f2bf(f.z - bf2f(h.z));
    h.w = f2bf(f.w); l.w = f2bf(f.w - bf2f(h.w));
    ((ushort4*)oh)[g] = h;
    ((ushort4*)ol)[g] = l;
}

// ---------------- MFMA GEMM (unchanged, verified) ----------------
__global__ __launch_bounds__(256) void gemm_mfma(const ushort* __restrict__ Ah,
                                                 const ushort* __restrict__ Al,
                                                 const ushort* __restrict__ Wh,
                                                 const ushort* __restrict__ Wl,
                                                 const float* __restrict__ bih,
                                                 const float* __restrict__ bhh,
                                                 float* __restrict__ out, int K)
{
    __shared__ ushort lds[2][128 * 72];
    const int tid = threadIdx.x;
    const int w = tid >> 6, ln = tid & 63;
    const int m0 = blockIdx.y * 128, n0 = blockIdx.x * 128;
    const int arow = (w >> 1) * 64, bcol = (w & 1) * 64;
    const int lm = ln & 15, lk = (ln >> 4) * 8;
    const int sr = tid >> 3, sc = (tid & 7) * 8;

    f32x4 acc[4][4] = {};

#pragma unroll
    for (int s = 0; s < 3; ++s) {
        const ushort* Asrc = (s < 2) ? Ah : Al;
        const ushort* Bsrc = (s == 1) ? Wl : Wh;
        for (int k0 = 0; k0 < K; k0 += 64) {
            __syncthreads();
#pragma unroll
            for (int i = 0; i < 4; ++i) {
                int r = sr + 32 * i;
                *(uint4*)&lds[0][r * 72 + sc] =
                    *(const uint4*)(Asrc + (size_t)(m0 + r) * K + k0 + sc);
                *(uint4*)&lds[1][r * 72 + sc] =
                    *(const uint4*)(Bsrc + (size_t)(n0 + r) * K + k0 + sc);
            }
            __syncthreads();
#pragma unroll
            for (int ks = 0; ks < 2; ++ks) {
                bf16x8 af[4], bf[4];
#pragma unroll
                for (int i = 0; i < 4; ++i)
                    af[i] = *(const bf16x8*)&lds[0][(arow + i * 16 + lm) * 72 + ks * 32 + lk];
#pragma unroll
                for (int j = 0; j < 4; ++j)
                    bf[j] = *(const bf16x8*)&lds[1][(bcol + j * 16 + lm) * 72 + ks * 32 + lk];
#pragma unroll
                for (int i = 0; i < 4; ++i)
#pragma unroll
                    for (int j = 0; j < 4; ++j)
                        acc[i][j] = __builtin_amdgcn_mfma_f32_16x16x32_bf16(
                            af[i], bf[j], acc[i][j], 0, 0, 0);
            }
        }
    }

#pragma unroll
    for (int j = 0; j < 4; ++j) {
        const int n = n0 + bcol + j * 16 + lm;
        const float bsum = bih[n] + bhh[n];
#pragma unroll
        for (int i = 0; i < 4; ++i) {
            const int mrow = m0 + arow + i * 16 + (ln >> 4) * 4;
#pragma unroll
            for (int r = 0; r < 4; ++r) {
                const int m = mrow + r;
                const int bb = m >> 8, tt = m & 255;
                out[(size_t)(tt * 16 + bb) * GG + n] = acc[i][j][r] + bsum;
            }
        }
    }
}

__device__ __forceinline__ float sigf(float x) { return 1.0f / (1.0f + expf(-x)); }

// ---------------- per-layer LSTM scan: 128 WG x 512 thr, MFMA dot, tree barrier ------
// WG wg owns h-cols j0=8wg..8wg+7 -> 32 gate rows r: gate=r>>3, col=j0+(r&7).
// Wave w: tile t_w=w&1 (rows t_w*16..+15), kslice s_w=w>>1 (k [256*s_w,+256)).
// Wave w stages h chunks {2w,2w+1} (k [128w,+128)) into LDS (cross-wave reads -> sync).
__global__ __launch_bounds__(512, 1) void lstm_scan(const float* __restrict__ Whh,
                                                    const float* __restrict__ xg,
                                                    ushort* __restrict__ hseq_hi,
                                                    ushort* __restrict__ hseq_lo,
                                                    unsigned* __restrict__ hglob2p,
                                                    unsigned* __restrict__ bar,
                                                    unsigned wantbase)
{
    extern __shared__ float smem[];
    char* smb = (char*)smem;

    const int tid = threadIdx.x;
    const int wg  = blockIdx.x;
    const int j0  = wg << 3;
    const int w   = tid >> 6;
    const int ln  = tid & 63;
    const int m   = ln & 15;     // tile-row (A) / batch-col (B) lane index
    const int kq  = ln >> 4;     // k-quarter in K=32 MFMA tile
    const int t_w = w & 1;       // output tile (0: gates i,f ; 1: gates g,o)
    const int s_w = w >> 1;      // k-slice

    // ---- preload W fragments (step-invariant): 8 ksteps x (hi,lo)
    bf16x8 wf_hi[8], wf_lo[8];
    {
        const int r = t_w * 16 + m;                        // gate row in [0,32)
        const int grow = ((r >> 3) << 10) + j0 + (r & 7);
        const float* wrow = Whh + (size_t)grow * 1024 + (s_w << 8) + (kq << 3);
#pragma unroll
        for (int s = 0; s < 8; ++s) {
            float4 f0 = *(const float4*)(wrow + s * 32);
            float4 f1 = *(const float4*)(wrow + s * 32 + 4);
            float fv[8] = {f0.x, f0.y, f0.z, f0.w, f1.x, f1.y, f1.z, f1.w};
            bf16x8 h8, l8;
#pragma unroll
            for (int i = 0; i < 8; ++i) {
                unsigned short hb = f2bf(fv[i]);
                float rr = fv[i] - bf2f(hb);
                h8[i] = (short)hb;
                l8[i] = (short)f2bf(rr);
            }
            wf_hi[s] = h8;
            wf_lo[s] = l8;
        }
    }

    // staging lane mapping
    const int bidx = ln >> 4;
    const int jj   = ln & 15;
    const int kkloc = jj >> 1;
    const int sub   = (jj & 1) * 8;

    // xg mapping: thread tid <-> (r_x = tid>>4 in [0,32), b_x = tid&15)
    const int r_x = tid >> 4, b_x = tid & 15;
    const int grow_x = ((r_x >> 3) << 10) + j0 + (r_x & 7);

    // gate lanes (tid<64): q = col-pair, b = batch
    const int q = tid >> 4, bg = tid & 15;

    // barrier pointers (tid0): 8 groups of 16 WGs
    unsigned* arr  = bar + ((wg >> 4) << 4);
    unsigned* root = bar + 256;
    unsigned* genc = bar + 512 + ((wg >> 4) << 4);

    float cs0 = 0.0f, cs1 = 0.0f;    // c-state for cols j0+2q, j0+2q+1

    float xg_pref = xg[(size_t)(0 * 16 + b_x) * GG + grow_x];

    for (int t = 0; t < TT; ++t) {
        if (t > 0) {
            if (tid == 0) {
                const unsigned tgt = wantbase + (unsigned)t;
                while (__hip_atomic_load(genc, __ATOMIC_RELAXED, __HIP_MEMORY_SCOPE_AGENT) < tgt)
                    __builtin_amdgcn_s_sleep(1);
            }
        }
        __syncthreads();                       // release waves; also fences prev gate reads

        smem[XGB_F + tid] = xg_pref;           // stage xg(t) (visible after next sync)

        if (t > 0) {
            // h(t-1) packed from parity buffer -> regs (wave w: chunks 2w, 2w+1)
            const uint4* hload = (const uint4*)(hglob2p + (((t - 1) & 1) << 14));
            uint4 v[2][4];
#pragma unroll
            for (int cc = 0; cc < 2; ++cc) {
                const uint4* p = hload + ((w << 1) + cc) * 256 + ln;
                asm volatile(
                    "global_load_dwordx4 %0, %4, off sc0 sc1\n\t"
                    "global_load_dwordx4 %1, %4, off offset:1024 sc0 sc1\n\t"
                    "global_load_dwordx4 %2, %4, off offset:2048 sc0 sc1\n\t"
                    "global_load_dwordx4 %3, %4, off offset:3072 sc0 sc1"
                    : "=&v"(v[cc][0]), "=&v"(v[cc][1]), "=&v"(v[cc][2]), "=&v"(v[cc][3])
                    : "v"(p) : "memory");
            }
            asm volatile("s_waitcnt vmcnt(0)" ::: "memory");
            __builtin_amdgcn_sched_barrier(0);

            // unpack hi/lo -> LDS octet blocks [kk][b]
#pragma unroll
            for (int cc = 0; cc < 2; ++cc) {
                const int kk = ((w << 1) + cc) * 8 + kkloc;
#pragma unroll
                for (int i = 0; i < 4; ++i) {
                    const int b = (i << 2) + bidx;
                    uint4 pv = v[cc][i];
                    uint2 uh = {(pv.x & 0xFFFFu) | (pv.y << 16),
                                (pv.z & 0xFFFFu) | (pv.w << 16)};
                    uint2 ul = {(pv.x >> 16) | (pv.y & 0xFFFF0000u),
                                (pv.z >> 16) | (pv.w & 0xFFFF0000u)};
                    char* base = smb + kk * 272 + b * 16 + sub;
                    *(uint2*)(base) = uh;
                    *(uint2*)(base + HLO_B) = ul;
                }
            }
        }
        __syncthreads();                       // stage + xg visible to all waves

        f32x4 asum = {0.f, 0.f, 0.f, 0.f};
        if (t > 0) {
            f32x4 aA = {0.f, 0.f, 0.f, 0.f};
            f32x4 aB = {0.f, 0.f, 0.f, 0.f};
            f32x4 aC = {0.f, 0.f, 0.f, 0.f};
            const char* hb0 = smb + ((s_w << 5) + kq) * 272 + m * 16;
#pragma unroll
            for (int s = 0; s < 8; ++s) {
                bf16x8 bh = *(const bf16x8*)(hb0 + s * 1088);
                bf16x8 bl = *(const bf16x8*)(hb0 + HLO_B + s * 1088);
                aA = __builtin_amdgcn_mfma_f32_16x16x32_bf16(wf_hi[s], bh, aA, 0, 0, 0);
                aB = __builtin_amdgcn_mfma_f32_16x16x32_bf16(wf_hi[s], bl, aB, 0, 0, 0);
                aC = __builtin_amdgcn_mfma_f32_16x16x32_bf16(wf_lo[s], bh, aC, 0, 0, 0);
            }
            asum = aA + aB;
            asum = asum + aC;
        }

        // partials: D row = kq*4+reg (tile row), col = m (batch)
#pragma unroll
        for (int r = 0; r < 4; ++r)
            smem[PART_F + w * 272 + ((kq << 2) + r) * 17 + m] = asum[r];
        __syncthreads();

        // prefetch next xg (hides under gates + barrier)
        float xg_next = 0.f;
        if (t + 1 < TT)
            xg_next = xg[(size_t)((t + 1) * 16 + b_x) * GG + grow_x];

        if (tid < 64) {
            // fused reduce + gates for cols c0=2q, c1=2q+1
#pragma unroll
            for (int cc = 0; cc < 2; ++cc) {
                const int ch = 2 * q + cc;
                float iv = smem[XGB_F + (ch     ) * 16 + bg];
                float fv = smem[XGB_F + (ch +  8) * 16 + bg];
                float gv = smem[XGB_F + (ch + 16) * 16 + bg];
                float ov = smem[XGB_F + (ch + 24) * 16 + bg];
#pragma unroll
                for (int s = 0; s < 4; ++s) {
                    iv += smem[PART_F + (2 * s    ) * 272 + (ch    ) * 17 + bg];
                    fv += smem[PART_F + (2 * s    ) * 272 + (ch + 8) * 17 + bg];
                    gv += smem[PART_F + (2 * s + 1) * 272 + (ch    ) * 17 + bg];
                    ov += smem[PART_F + (2 * s + 1) * 272 + (ch + 8) * 17 + bg];
                }
                float& cs = cc ? cs1 : cs0;
                cs = sigf(fv) * cs + sigf(iv) * tanhf(gv);
                float hval = sigf(ov) * tanhf(cs);
                unsigned short hh_ = f2bf(hval);
                unsigned short hl_ = f2bf(hval - bf2f(hh_));
                unsigned pk = (unsigned)hh_ | ((unsigned)hl_ << 16);
                const int col = j0 + ch;
                unsigned* hdst = hglob2p + ((t & 1) << 14) +
                                 ((col >> 6) << 10) + (bg << 6) + (col & 63);
                asm volatile("global_store_dword %0, %1, off sc0 sc1"
                             :: "v"(hdst), "v"(pk) : "memory");
                // stash for hseq (stored after arrive, off sync path)
                if (cc == 0) { cs0 = cs; }
                smem[XGB_F + 512 + tid * 2 + cc] = __int_as_float((int)pk);
            }
        }

        if (t < TT - 1) {
            const unsigned target = wantbase + (unsigned)t + 1u;
            if (tid == 0) {
                asm volatile("s_waitcnt vmcnt(0)" ::: "memory");   // h stores acked
                unsigned a = __hip_atomic_fetch_add(arr, 1u, __ATOMIC_RELAXED, __HIP_MEMORY_SCOPE_AGENT);
                if (a == 15u) {
                    unsigned ra = __hip_atomic_fetch_add(root, 1u, __ATOMIC_RELAXED, __HIP_MEMORY_SCOPE_AGENT);
                    if (ra == 7u) {
                        __hip_atomic_store(root, 0u, __ATOMIC_RELAXED, __HIP_MEMORY_SCOPE_AGENT);
#pragma unroll
                        for (int i = 0; i < 8; ++i)
                            __hip_atomic_store(bar + (i << 4), 0u, __ATOMIC_RELAXED, __HIP_MEMORY_SCOPE_AGENT);
                        asm volatile("s_waitcnt vmcnt(0)" ::: "memory");
#pragma unroll
                        for (int i = 0; i < 8; ++i)
                            __hip_atomic_store(bar + 512 + (i << 4), target,
                                               __ATOMIC_RELAXED, __HIP_MEMORY_SCOPE_AGENT);
                    }
                }
            }
        }
        if (tid < 64) {   // hseq stores after arrive (plain, kernel-end visibility)
#pragma unroll
            for (int cc = 0; cc < 2; ++cc) {
                unsigned pk = (unsigned)__float_as_int(smem[XGB_F + 512 + tid * 2 + cc]);
                const int col = j0 + 2 * q + cc;
                size_t idx = (size_t)(bg * TT + t) * HH + col;
                hseq_hi[idx] = (ushort)(pk & 0xFFFFu);
                hseq_lo[idx] = (ushort)(pk >> 16);
            }
        }
        xg_pref = xg_next;
    }
}

// ---------------- FC head ----------------
__global__ void fc_relu_split(const ushort* __restrict__ ih, const ushort* __restrict__ il,
                              const float* __restrict__ w, const float* __restrict__ b,
                              float* __restrict__ out, int N, int K)
{
    int g = blockIdx.x * blockDim.x + threadIdx.x;
    if (g >= BB * N) return;
    int bi = g / N, n = g - bi * N;
    const ushort* ph = ih + (size_t)(bi * 256 + 255) * 1024;
    const ushort* pl = il + (size_t)(bi * 256 + 255) * 1024;
    const float* wp = w + (size_t)n * K;
    float s = 0.f;
    for (int k = 0; k < K; k += 4) {
        ushort4 uh = *(const ushort4*)(ph + k);
        ushort4 ul = *(const ushort4*)(pl + k);
        float4 qv = *(const float4*)(wp + k);
        s += (bf2f(uh.x) + bf2f(ul.x)) * qv.x + (bf2f(uh.y) + bf2f(ul.y)) * qv.y +
             (bf2f(uh.z) + bf2f(ul.z)) * qv.z + (bf2f(uh.w) + bf2f(ul.w)) * qv.w;
    }
    s += b[n];
    out[g] = fmaxf(s, 0.f);
}

__global__ void fc_relu(const float* __restrict__ in, const float* __restrict__ w,
                        const float* __restrict__ b, float* __restrict__ out,
                        int N, int K, int do_relu)
{
    int g = blockIdx.x * blockDim.x + threadIdx.x;
    if (g >= BB * N) return;
    int bi = g / N, n = g - bi * N;
    const float* ip = in + (size_t)bi * K;
    const float* wp = w + (size_t)n * K;
    float s = 0.f;
    for (int k = 0; k < K; k += 4) {
        float4 a = *(const float4*)(ip + k);
        float4 qv = *(const float4*)(wp + k);
        s += a.x * qv.x + a.y * qv.y + a.z * qv.z + a.w * qv.w;
    }
    s += b[n];
    if (do_relu) s = fmaxf(s, 0.f);
    out[g] = s;
}

// ---------------- launch ----------------
extern "C" void kernel_launch(void* const* d_in, const int* in_sizes, int n_in,
                              void* d_out, int out_size, void* d_ws, size_t ws_size,
                              hipStream_t stream)
{
    const float* x    = (const float*)d_in[0];
    const float* Wih0 = (const float*)d_in[1];
    const float* WihR = (const float*)d_in[2];
    const float* Whh  = (const float*)d_in[3];
    const float* bih  = (const float*)d_in[4];
    const float* bhh  = (const float*)d_in[5];
    const float* fc1w = (const float*)d_in[6];
    const float* fc1b = (const float*)d_in[7];
    const float* fc2w = (const float*)d_in[8];
    const float* fc2b = (const float*)d_in[9];
    const float* fc3w = (const float*)d_in[10];
    const float* fc3b = (const float*)d_in[11];
    float* out = (float*)d_out;
    char* ws = (char*)d_ws;

    float* xg       = (float*)(ws + XG_OFF);
    ushort* reg_[2] = {(ushort*)(ws + REG0_OFF), (ushort*)(ws + REG1_OFF)};
    unsigned* hglob2p = (unsigned*)(ws + HG2_OFF);
    float* fc1o     = (float*)(ws + FC1_OFF);
    float* fc2o     = (float*)(ws + FC2_OFF);
    unsigned* bar   = (unsigned*)(ws + BAR_OFF);

    (void)hipFuncSetAttribute((const void*)lstm_scan,
                              hipFuncAttributeMaxDynamicSharedMemorySize, SMEM_BYTES);
    (void)hipMemsetAsync(ws + BAR_OFF, 0, 4096, stream);   // arrive/root/gen = 0 (monotonic)

    // layer-0 X conversion into region 1 (dead before Wcv(1) is written)
    ushort* xcv_hi = reg_[1];
    ushort* xcv_lo = reg_[1] + 2097152;
    conv_split<<<2048, 256, 0, stream>>>(x, xcv_hi, xcv_lo, (BB * TT * IN0) / 4);

    for (int l = 0; l < NLAYERS; ++l) {
        const int K = (l == 0) ? IN0 : HH;
        const float* Wl_f = (l == 0) ? Wih0 : (WihR + (size_t)(l - 1) * GG * HH);

        ushort* wh = reg_[l & 1];
        ushort* wl = wh + 4194304;
        const int n4 = GG * K / 4;
        conv_split<<<(n4 + 255) / 256, 256, 0, stream>>>(Wl_f, wh, wl, n4);

        const ushort* ah = (l == 0) ? xcv_hi : reg_[(l - 1) & 1];
        const ushort* al = (l == 0) ? xcv_lo : (reg_[(l - 1) & 1] + 4194304);

        gemm_mfma<<<dim3(32, 32), 256, 0, stream>>>(
            ah, al, wh, wl, bih + (size_t)l * GG, bhh + (size_t)l * GG, xg, K);

        ushort* hs_hi = reg_[l & 1];
        ushort* hs_lo = reg_[l & 1] + 4194304;
        const float* whh_l = Whh + (size_t)l * GG * HH;
        unsigned wantbase = (unsigned)(TT * l);
        void* args[7] = {(void*)&whh_l, (void*)&xg, (void*)&hs_hi, (void*)&hs_lo,
                         (void*)&hglob2p, (void*)&bar, (void*)&wantbase};
        hipError_t e = hipLaunchCooperativeKernel((void*)lstm_scan, dim3(NWG), dim3(512),
                                                  args, SMEM_BYTES, stream);
        if (e != hipSuccess) {
            lstm_scan<<<dim3(NWG), dim3(512), SMEM_BYTES, stream>>>(
                whh_l, xg, hs_hi, hs_lo, hglob2p, bar, wantbase);
        }
    }

    // FC head: hs(7) is in region 1
    fc_relu_split<<<32, 256, 0, stream>>>(reg_[1], reg_[1] + 4194304,
                                          fc1w, fc1b, fc1o, 512, 1024);
    fc_relu<<<16, 256, 0, stream>>>(fc1o, fc2w, fc2b, fc2o, 256, 512, 1);
    fc_relu<<<1, 16, 0, stream>>>(fc2o, fc3w, fc3b, out, 1, 256, 0);
}